// Round 4
// baseline (2095.975 us; speedup 1.0000x reference)
//
#include <hip/hip_runtime.h>
#include <cstdint>

#define NN 100000
#define NE 400000
#define NG 2048
#define H  32
#define ED 16
#define NPB 20    // src-nodes per group in k_fused (NN % 20 == 0)
#define GNPB 20   // nodes per group in k_gru2
#define SMP 36    // padded row stride for sm/sh in k_gru2

// ---------------- lin0: feat = relu(x @ W0^T + b0) ----------------
__global__ __launch_bounds__(256) void k_lin0(const float* __restrict__ x,
                                              const float* __restrict__ W0,
                                              const float* __restrict__ b0,
                                              float* __restrict__ feat) {
  __shared__ float w0t[1024];                  // W0^T[i][o]
  int t = threadIdx.x;
  for (int idx = t; idx < 1024; idx += 256) {
    int o = idx >> 5, i = idx & 31;
    w0t[(i << 5) | o] = W0[idx];
  }
  __syncthreads();
  int id = blockIdx.x * 256 + t;               // N*32 threads exactly
  int n = id >> 5, o = id & 31;
  const float* xr = x + n * H;
  float acc = b0[o];
#pragma unroll
  for (int i = 0; i < H; ++i) acc = fmaf(xr[i], w0t[(i << 5) | o], acc);
  feat[id] = fmaxf(acc, 0.f);
}

// ---- CSR build (once per launch): histogram, scan, scatter ----
__global__ __launch_bounds__(256) void k_hist(const int* __restrict__ ei,
                                              int* __restrict__ deg) {
  int e = blockIdx.x * 256 + threadIdx.x;
  if (e < NE) atomicAdd(&deg[ei[e]], 1);
}

__global__ __launch_bounds__(1024) void k_scan(const int* __restrict__ deg,
                                               int* __restrict__ rowptr,
                                               int* __restrict__ nextp) {
  __shared__ int part[1024];
  int t = threadIdx.x;
  const int CH = (NN + 1023) / 1024;           // 98
  int st = t * CH, en = st + CH;
  if (st > NN) st = NN;
  if (en > NN) en = NN;
  int s = 0;
  for (int i = st; i < en; ++i) s += deg[i];
  part[t] = s;
  __syncthreads();
  for (int off = 1; off < 1024; off <<= 1) {
    int v = (t >= off) ? part[t - off] : 0;
    __syncthreads();
    part[t] += v;
    __syncthreads();
  }
  int run = (t == 0) ? 0 : part[t - 1];
  for (int i = st; i < en; ++i) {
    rowptr[i] = run;
    nextp[i] = run;
    run += deg[i];
  }
  if (t == 0) rowptr[NN] = NE;
}

__global__ __launch_bounds__(256) void k_scatter(const int* __restrict__ ei,
                                                 const float* __restrict__ ea,
                                                 int* __restrict__ nextp,
                                                 int* __restrict__ src_perm,
                                                 int* __restrict__ dst_perm,
                                                 float* __restrict__ ea_perm) {
  int e = blockIdx.x * 256 + threadIdx.x;
  if (e >= NE) return;
  int src = ei[e], dst = ei[NE + e];
  int p = atomicAdd(&nextp[src], 1);
  src_perm[p] = src;
  dst_perm[p] = dst;
  const float4* s4 = (const float4*)(ea + (size_t)e * ED);
  float4* d4 = (float4*)(ea_perm + (size_t)p * ED);
  d4[0] = s4[0]; d4[1] = s4[1]; d4[2] = s4[2]; d4[3] = s4[3];
}

// ---- per-iteration: agg init (root term + bconv) ----
__global__ __launch_bounds__(256) void k_pre(const float* __restrict__ feat,
                                             const float* __restrict__ Wroot,
                                             const float* __restrict__ bconv,
                                             float* __restrict__ agg) {
  __shared__ float wrt[1024];                  // Wroot^T[i][o]
  int t = threadIdx.x;
  for (int idx = t; idx < 1024; idx += 256) {
    int o = idx >> 5, i = idx & 31;
    wrt[(i << 5) | o] = Wroot[idx];
  }
  __syncthreads();
  int id = blockIdx.x * 256 + t;               // N*32
  int n = id >> 5, o = id & 31;
  const float* fr = feat + n * H;
  float a = bconv[o];
#pragma unroll
  for (int i = 0; i < H; ++i) a = fmaf(fr[i], wrt[(i << 5) | o], a);
  agg[id] = a;
}

// ---- fused g+edge: per src-group compute g rows in LDS, apply out-edges ----
__global__ __launch_bounds__(256) void k_fused(const float* __restrict__ feat,
                                               const float* __restrict__ We,
                                               const float* __restrict__ be,
                                               const int* __restrict__ rowptr,
                                               const int* __restrict__ src_perm,
                                               const int* __restrict__ dst_perm,
                                               const float* __restrict__ ea_perm,
                                               float* __restrict__ agg) {
  __shared__ float sf[NPB * 32];
  __shared__ float snb[NPB * 32];
  __shared__ float sg[NPB * 512];              // 40 KB, XOR-swizzled float4 slots
  __shared__ float sbe[1024];
  int t = threadIdx.x;
  int cj = t & 127, half = t >> 7;

  // We column into registers once (grid-strided blocks amortize this)
  const float4* We4 = (const float4*)We;
  float4 wcol[32];
#pragma unroll
  for (int i = 0; i < 32; ++i) wcol[i] = We4[i * 128 + cj];
  for (int idx = t; idx < 1024; idx += 256) sbe[idx] = be[idx];
  int physc = (cj & ~7) | ((cj ^ (cj >> 3)) & 7);   // swizzled write slot

  for (int g0 = blockIdx.x; g0 < NN / NPB; g0 += gridDim.x) {
    int base = g0 * NPB;
    __syncthreads();                            // protect LDS from prev group
    for (int idx = t; idx < NPB * 32; idx += 256) sf[idx] = feat[base * 32 + idx];
    __syncthreads();
    // nodeb
    {
      int o = t & 31;
      for (int ln = t >> 5; ln < NPB; ln += 8) {
        float nb = 0.f;
#pragma unroll
        for (int i = 0; i < 32; ++i) nb = fmaf(sf[ln * 32 + i], sbe[(i << 5) | o], nb);
        snb[ln * 32 + o] = nb;
      }
    }
    // g rows
    for (int k = 0; k < NPB / 2; ++k) {
      int ln = 2 * k + half;
      float4 acc = {0.f, 0.f, 0.f, 0.f};
#pragma unroll
      for (int i = 0; i < 32; ++i) {
        float fi = sf[ln * 32 + i];
        acc.x = fmaf(fi, wcol[i].x, acc.x);
        acc.y = fmaf(fi, wcol[i].y, acc.y);
        acc.z = fmaf(fi, wcol[i].z, acc.z);
        acc.w = fmaf(fi, wcol[i].w, acc.w);
      }
      *(float4*)(sg + ln * 512 + physc * 4) = acc;
    }
    __syncthreads();
    // edges of this group: contiguous [rowptr[base], rowptr[base+NPB])
    int e0 = rowptr[base], e1 = rowptr[base + NPB];
    int o = t & 31, slot = t >> 5;
    for (int e = e0 + slot; e < e1; e += 8) {
      int src = src_perm[e];
      int dst = dst_perm[e];
      int ln = src - base;
      const float4* e4 = (const float4*)(ea_perm + (size_t)e * ED);
      float acc = snb[ln * 32 + o];
#pragma unroll
      for (int q = 0; q < 4; ++q) {
        int s = o * 4 + q;
        int ph = (s & ~7) | ((s ^ (s >> 3)) & 7);
        float4 gv = *(const float4*)(sg + ln * 512 + ph * 4);
        float4 ev = e4[q];
        acc = fmaf(ev.x, gv.x, acc);
        acc = fmaf(ev.y, gv.y, acc);
        acc = fmaf(ev.z, gv.z, acc);
        acc = fmaf(ev.w, gv.w, acc);
      }
      unsafeAtomicAdd(&agg[(size_t)dst * 32 + o], acc);
    }
  }
}

// ---- fused GRU: gi = relu(agg)@Wih^T, gh = h@Whh^T, then gates ----
__global__ __launch_bounds__(256) void k_gru2(const float* __restrict__ agg,
                                              const float* __restrict__ Wih,
                                              const float* __restrict__ bih,
                                              const float* __restrict__ Whh,
                                              const float* __restrict__ bhh,
                                              float* __restrict__ feat) {
  __shared__ float wsw[6144];                  // XOR-swizzled [m][r][i^(r&31)]
  __shared__ float sm[GNPB * SMP];
  __shared__ float sh[GNPB * SMP];
  __shared__ float gil[GNPB * 96];
  __shared__ float ghl[GNPB * 96];
  int t = threadIdx.x;

  for (int idx = t; idx < 3072; idx += 256) {
    int r = idx >> 5, i = idx & 31;
    int sw = (r << 5) | (i ^ (r & 31));
    wsw[sw]        = Wih[idx];
    wsw[3072 + sw] = Whh[idx];
  }
  __syncthreads();

  int task = t / 5;
  int slot = t - task * 5;
  bool act = task < 48;
  int c4 = (act ? (task < 24 ? task : task - 24) : 0) * 4;
  int mbase = (task < 24) ? 0 : 3072;
  float4 wcol[32];
  if (act) {
#pragma unroll
    for (int i = 0; i < 32; ++i) {
      wcol[i].x = wsw[mbase + ((c4 + 0) << 5) + (i ^ ((c4 + 0) & 31))];
      wcol[i].y = wsw[mbase + ((c4 + 1) << 5) + (i ^ ((c4 + 1) & 31))];
      wcol[i].z = wsw[mbase + ((c4 + 2) << 5) + (i ^ ((c4 + 2) & 31))];
      wcol[i].w = wsw[mbase + ((c4 + 3) << 5) + (i ^ ((c4 + 3) & 31))];
    }
  }

  for (int g0 = blockIdx.x; g0 < NN / GNPB; g0 += gridDim.x) {
    size_t base32 = (size_t)g0 * GNPB * 32;
    for (int idx = t; idx < GNPB * 32; idx += 256) {
      int ln = idx >> 5, i = idx & 31;
      sm[ln * SMP + i] = fmaxf(agg[base32 + idx], 0.f);
      sh[ln * SMP + i] = feat[base32 + idx];
    }
    __syncthreads();
    if (act) {
      const float* src = (task < 24) ? sm : sh;
      float* dstbuf = (task < 24) ? gil : ghl;
#pragma unroll
      for (int p = 0; p < 4; ++p) {
        int ln = 5 * p + slot;
        const float4* srow = (const float4*)(src + ln * SMP);
        float4 acc = {0.f, 0.f, 0.f, 0.f};
#pragma unroll
        for (int q = 0; q < 8; ++q) {
          float4 f = srow[q];
          float4 w0 = wcol[4 * q], w1 = wcol[4 * q + 1];
          float4 w2 = wcol[4 * q + 2], w3 = wcol[4 * q + 3];
          acc.x = fmaf(f.x, w0.x, acc.x); acc.y = fmaf(f.x, w0.y, acc.y);
          acc.z = fmaf(f.x, w0.z, acc.z); acc.w = fmaf(f.x, w0.w, acc.w);
          acc.x = fmaf(f.y, w1.x, acc.x); acc.y = fmaf(f.y, w1.y, acc.y);
          acc.z = fmaf(f.y, w1.z, acc.z); acc.w = fmaf(f.y, w1.w, acc.w);
          acc.x = fmaf(f.z, w2.x, acc.x); acc.y = fmaf(f.z, w2.y, acc.y);
          acc.z = fmaf(f.z, w2.z, acc.z); acc.w = fmaf(f.z, w2.w, acc.w);
          acc.x = fmaf(f.w, w3.x, acc.x); acc.y = fmaf(f.w, w3.y, acc.y);
          acc.z = fmaf(f.w, w3.z, acc.z); acc.w = fmaf(f.w, w3.w, acc.w);
        }
        *(float4*)(dstbuf + ln * 96 + c4) = acc;
      }
    }
    __syncthreads();
    for (int idx = t; idx < GNPB * 32; idx += 256) {
      int ln = idx >> 5, o = idx & 31;
      float gir = gil[ln * 96 + o]       + bih[o];
      float giz = gil[ln * 96 + 32 + o]  + bih[32 + o];
      float gin = gil[ln * 96 + 64 + o]  + bih[64 + o];
      float ghr = ghl[ln * 96 + o]       + bhh[o];
      float ghz = ghl[ln * 96 + 32 + o]  + bhh[32 + o];
      float ghn = ghl[ln * 96 + 64 + o]  + bhh[64 + o];
      float h = sh[ln * SMP + o];
      float r = 1.f / (1.f + expf(-(gir + ghr)));
      float z = 1.f / (1.f + expf(-(giz + ghz)));
      float nn = tanhf(fmaf(r, ghn, gin));
      feat[base32 + idx] = (1.f - z) * nn + z * h;
    }
    __syncthreads();
  }
}

// ---- global mean pool ----
__global__ __launch_bounds__(256) void k_pool(const float* __restrict__ feat,
                                              const int* __restrict__ batch,
                                              float* __restrict__ pooled,
                                              float* __restrict__ cnts) {
  int id = blockIdx.x * 256 + threadIdx.x;     // N*32
  int n = id >> 5, o = id & 31;
  int b = batch[n];
  unsafeAtomicAdd(&pooled[b * H + o], feat[id]);
  if (o == 0) unsafeAtomicAdd(&cnts[b], 1.f);
}

// ---- final head ----
__global__ __launch_bounds__(256) void k_final(const float* __restrict__ pooled,
                                               const float* __restrict__ cnts,
                                               const float* __restrict__ W1,
                                               const float* __restrict__ b1,
                                               float* __restrict__ y) {
  int gph = blockIdx.x * 256 + threadIdx.x;
  if (gph >= NG) return;
  float c = fmaxf(cnts[gph], 1.f);
  float acc = 0.f;
#pragma unroll
  for (int o = 0; o < H; ++o) acc = fmaf(pooled[gph * H + o], W1[o], acc);
  y[gph] = acc / c + b1[0];
}

extern "C" void kernel_launch(void* const* d_in, const int* in_sizes, int n_in,
                              void* d_out, int out_size, void* d_ws, size_t ws_size,
                              hipStream_t stream) {
  const float* x     = (const float*)d_in[0];
  const int*   ei    = (const int*)d_in[1];
  const float* ea    = (const float*)d_in[2];
  const int*   batch = (const int*)d_in[3];
  const float* W0    = (const float*)d_in[4];
  const float* b0    = (const float*)d_in[5];
  const float* We    = (const float*)d_in[6];
  const float* be    = (const float*)d_in[7];
  const float* Wroot = (const float*)d_in[8];
  const float* bconv = (const float*)d_in[9];
  const float* Wih   = (const float*)d_in[10];
  const float* bih   = (const float*)d_in[11];
  const float* Whh   = (const float*)d_in[12];
  const float* bhh   = (const float*)d_in[13];
  const float* W1    = (const float*)d_in[14];
  const float* b1    = (const float*)d_in[15];

  float* ws       = (float*)d_ws;
  float* feat     = ws;                         // 3,200,000
  float* agg      = ws + 3200000;               // 3,200,000
  float* pooled   = ws + 6400000;               // 65,536
  float* cnts     = ws + 6465536;               // 2,048
  float* ea_perm  = ws + 6467584;               // 6,400,000 (16B-aligned)
  int*   ibuf     = (int*)(ws + 12867584);
  int*   deg      = ibuf;                       // 100,000
  int*   rowptr   = ibuf + 100000;              // 100,001
  int*   nextp    = ibuf + 200004;              // 100,000
  int*   src_perm = ibuf + 300004;              // 400,000
  int*   dst_perm = ibuf + 700004;              // 400,000

  const int NB_NODE = (NN * H) / 256;           // 12500
  const int NB_E    = (NE + 255) / 256;         // 1563

  // one-time CSR build (iteration-invariant)
  hipMemsetAsync(deg, 0, NN * sizeof(int), stream);
  k_hist<<<NB_E, 256, 0, stream>>>(ei, deg);
  k_scan<<<1, 1024, 0, stream>>>(deg, rowptr, nextp);
  k_scatter<<<NB_E, 256, 0, stream>>>(ei, ea, nextp, src_perm, dst_perm, ea_perm);

  k_lin0<<<NB_NODE, 256, 0, stream>>>(x, W0, b0, feat);
  for (int it = 0; it < 3; ++it) {
    k_pre<<<NB_NODE, 256, 0, stream>>>(feat, Wroot, bconv, agg);
    k_fused<<<2500, 256, 0, stream>>>(feat, We, be, rowptr, src_perm, dst_perm,
                                      ea_perm, agg);
    k_gru2<<<768, 256, 0, stream>>>(agg, Wih, bih, Whh, bhh, feat);
  }
  hipMemsetAsync(pooled, 0, (size_t)(NG * H + NG) * 4, stream);
  k_pool<<<NB_NODE, 256, 0, stream>>>(feat, batch, pooled, cnts);
  k_final<<<(NG + 255) / 256, 256, 0, stream>>>(pooled, cnts, W1, b1, (float*)d_out);
}

// Round 5
// 875.952 us; speedup vs baseline: 2.3928x; 2.3928x over previous
//
#include <hip/hip_runtime.h>
#include <cstdint>

#define NN 100000
#define NE 400000
#define NG 2048
#define H  32
#define ED 16
#define NPB 16    // src-nodes per block in k_fused (100000 % 16 == 0 -> 6250 blocks)
#define GNPB 20   // nodes per group in k_gru2
#define SMP 36    // padded row stride for sm/sh in k_gru2

// ---------------- lin0: feat = relu(x @ W0^T + b0) ----------------
__global__ __launch_bounds__(256) void k_lin0(const float* __restrict__ x,
                                              const float* __restrict__ W0,
                                              const float* __restrict__ b0,
                                              float* __restrict__ feat) {
  __shared__ float w0t[1024];                  // W0^T[i][o]
  int t = threadIdx.x;
  for (int idx = t; idx < 1024; idx += 256) {
    int o = idx >> 5, i = idx & 31;
    w0t[(i << 5) | o] = W0[idx];
  }
  __syncthreads();
  int id = blockIdx.x * 256 + t;               // N*32 threads exactly
  int n = id >> 5, o = id & 31;
  const float* xr = x + n * H;
  float acc = b0[o];
#pragma unroll
  for (int i = 0; i < H; ++i) acc = fmaf(xr[i], w0t[(i << 5) | o], acc);
  feat[id] = fmaxf(acc, 0.f);
}

// ---- CSR build (once per launch): histogram, scan, scatter ----
__global__ __launch_bounds__(256) void k_hist(const int* __restrict__ ei,
                                              int* __restrict__ deg) {
  int e = blockIdx.x * 256 + threadIdx.x;
  if (e < NE) atomicAdd(&deg[ei[e]], 1);
}

__global__ __launch_bounds__(1024) void k_scan(const int* __restrict__ deg,
                                               int* __restrict__ rowptr,
                                               int* __restrict__ nextp) {
  __shared__ int part[1024];
  int t = threadIdx.x;
  const int CH = (NN + 1023) / 1024;           // 98
  int st = t * CH, en = st + CH;
  if (st > NN) st = NN;
  if (en > NN) en = NN;
  int s = 0;
  for (int i = st; i < en; ++i) s += deg[i];
  part[t] = s;
  __syncthreads();
  for (int off = 1; off < 1024; off <<= 1) {
    int v = (t >= off) ? part[t - off] : 0;
    __syncthreads();
    part[t] += v;
    __syncthreads();
  }
  int run = (t == 0) ? 0 : part[t - 1];
  for (int i = st; i < en; ++i) {
    rowptr[i] = run;
    nextp[i] = run;
    run += deg[i];
  }
  if (t == 0) rowptr[NN] = NE;
}

__global__ __launch_bounds__(256) void k_scatter(const int* __restrict__ ei,
                                                 const float* __restrict__ ea,
                                                 int* __restrict__ nextp,
                                                 int* __restrict__ src_perm,
                                                 int* __restrict__ dst_perm,
                                                 float* __restrict__ ea_perm) {
  int e = blockIdx.x * 256 + threadIdx.x;
  if (e >= NE) return;
  int src = ei[e], dst = ei[NE + e];
  int p = atomicAdd(&nextp[src], 1);
  src_perm[p] = src;
  dst_perm[p] = dst;
  const float4* s4 = (const float4*)(ea + (size_t)e * ED);
  float4* d4 = (float4*)(ea_perm + (size_t)p * ED);
  d4[0] = s4[0]; d4[1] = s4[1]; d4[2] = s4[2]; d4[3] = s4[3];
}

// ---- per-iteration: agg init (root term + bconv) ----
__global__ __launch_bounds__(256) void k_pre(const float* __restrict__ feat,
                                             const float* __restrict__ Wroot,
                                             const float* __restrict__ bconv,
                                             float* __restrict__ agg) {
  __shared__ float wrt[1024];                  // Wroot^T[i][o]
  int t = threadIdx.x;
  for (int idx = t; idx < 1024; idx += 256) {
    int o = idx >> 5, i = idx & 31;
    wrt[(i << 5) | o] = Wroot[idx];
  }
  __syncthreads();
  int id = blockIdx.x * 256 + t;               // N*32
  int n = id >> 5, o = id & 31;
  const float* fr = feat + n * H;
  float a = bconv[o];
#pragma unroll
  for (int i = 0; i < H; ++i) a = fmaf(fr[i], wrt[(i << 5) | o], a);
  agg[id] = a;
}

// ---- fused g+edge v2: low-VGPR, conflict-free LDS, one src-group per block ----
// sg layout: logical float4-slot s of row ln stored at phys slot (s&3)*32+(s>>2),
// i.e. sg4[ln*128 + q*32 + o] = g[ln][ (o*4+q)*4 .. +3 ]  (q=s&3, o=s>>2).
// Write side (lanes = consecutive cj): 8 words/bank, conflict-free.
// Read side (lane o reads q*32+o): consecutive lanes, conflict-free.
__global__ __launch_bounds__(256) void k_fused(const float* __restrict__ feat,
                                               const float* __restrict__ We,
                                               const float* __restrict__ be,
                                               const int* __restrict__ rowptr,
                                               const int* __restrict__ src_perm,
                                               const int* __restrict__ dst_perm,
                                               const float* __restrict__ ea_perm,
                                               float* __restrict__ agg) {
  __shared__ float sf[NPB * 32];               // 2 KB
  __shared__ float snb[NPB * 32];              // 2 KB
  __shared__ float sg[NPB * 512];              // 32 KB
  __shared__ float sbe[1024];                  // 4 KB
  int t = threadIdx.x;
  int base = blockIdx.x * NPB;                 // grid = NN/NPB = 6250

  for (int idx = t; idx < NPB * 32; idx += 256) sf[idx] = feat[base * 32 + idx];
  for (int idx = t; idx < 1024; idx += 256) sbe[idx] = be[idx];
  __syncthreads();

  // nodeb[ln][o] = sum_i sf[ln][i] * be[i*32+o]
  {
    int o = t & 31;
    for (int ln = t >> 5; ln < NPB; ln += 8) {
      float nb = 0.f;
#pragma unroll
      for (int i = 0; i < 32; ++i) nb = fmaf(sf[ln * 32 + i], sbe[(i << 5) | o], nb);
      snb[ln * 32 + o] = nb;
    }
  }
  // g rows: thread = column cj for 8 nodes; We streamed from L2
  {
    int cj = t & 127, nh = t >> 7;
    const float4* We4 = (const float4*)We;     // [32][128] float4
    float4 acc[8];
#pragma unroll
    for (int j = 0; j < 8; ++j) acc[j] = make_float4(0.f, 0.f, 0.f, 0.f);
    for (int i = 0; i < 32; ++i) {
      float4 w = We4[i * 128 + cj];
#pragma unroll
      for (int j = 0; j < 8; ++j) {
        float fi = sf[(nh * 8 + j) * 32 + i];
        acc[j].x = fmaf(fi, w.x, acc[j].x);
        acc[j].y = fmaf(fi, w.y, acc[j].y);
        acc[j].z = fmaf(fi, w.z, acc[j].z);
        acc[j].w = fmaf(fi, w.w, acc[j].w);
      }
    }
    float4* sg4 = (float4*)sg;
    int pslot = (cj & 3) * 32 + (cj >> 2);
#pragma unroll
    for (int j = 0; j < 8; ++j) sg4[(nh * 8 + j) * 128 + pslot] = acc[j];
  }
  __syncthreads();

  // edges of this group: contiguous [rowptr[base], rowptr[base+NPB])
  int e0 = rowptr[base], e1 = rowptr[base + NPB];
  int o = t & 31, slot = t >> 5;
  const float4* sg4 = (const float4*)sg;
  for (int e = e0 + slot; e < e1; e += 8) {
    int src = src_perm[e];
    int dst = dst_perm[e];
    int ln = src - base;
    const float4* e4 = (const float4*)(ea_perm + (size_t)e * ED);
    float acc = snb[ln * 32 + o];
#pragma unroll
    for (int q = 0; q < 4; ++q) {
      float4 gv = sg4[ln * 128 + q * 32 + o];
      float4 ev = e4[q];
      acc = fmaf(ev.x, gv.x, acc);
      acc = fmaf(ev.y, gv.y, acc);
      acc = fmaf(ev.z, gv.z, acc);
      acc = fmaf(ev.w, gv.w, acc);
    }
    unsafeAtomicAdd(&agg[(size_t)dst * 32 + o], acc);
  }
}

// ---- fused GRU: gi = relu(agg)@Wih^T, gh = h@Whh^T, then gates ----
__global__ __launch_bounds__(256) void k_gru2(const float* __restrict__ agg,
                                              const float* __restrict__ Wih,
                                              const float* __restrict__ bih,
                                              const float* __restrict__ Whh,
                                              const float* __restrict__ bhh,
                                              float* __restrict__ feat) {
  __shared__ float wsw[6144];                  // XOR-swizzled [m][r][i^(r&31)]
  __shared__ float sm[GNPB * SMP];
  __shared__ float sh[GNPB * SMP];
  __shared__ float gil[GNPB * 96];
  __shared__ float ghl[GNPB * 96];
  int t = threadIdx.x;

  for (int idx = t; idx < 3072; idx += 256) {
    int r = idx >> 5, i = idx & 31;
    int sw = (r << 5) | (i ^ (r & 31));
    wsw[sw]        = Wih[idx];
    wsw[3072 + sw] = Whh[idx];
  }
  __syncthreads();

  int task = t / 5;
  int slot = t - task * 5;
  bool act = task < 48;
  int c4 = (act ? (task < 24 ? task : task - 24) : 0) * 4;
  int mbase = (task < 24) ? 0 : 3072;
  float4 wcol[32];
  if (act) {
#pragma unroll
    for (int i = 0; i < 32; ++i) {
      wcol[i].x = wsw[mbase + ((c4 + 0) << 5) + (i ^ ((c4 + 0) & 31))];
      wcol[i].y = wsw[mbase + ((c4 + 1) << 5) + (i ^ ((c4 + 1) & 31))];
      wcol[i].z = wsw[mbase + ((c4 + 2) << 5) + (i ^ ((c4 + 2) & 31))];
      wcol[i].w = wsw[mbase + ((c4 + 3) << 5) + (i ^ ((c4 + 3) & 31))];
    }
  }

  for (int g0 = blockIdx.x; g0 < NN / GNPB; g0 += gridDim.x) {
    size_t base32 = (size_t)g0 * GNPB * 32;
    for (int idx = t; idx < GNPB * 32; idx += 256) {
      int ln = idx >> 5, i = idx & 31;
      sm[ln * SMP + i] = fmaxf(agg[base32 + idx], 0.f);
      sh[ln * SMP + i] = feat[base32 + idx];
    }
    __syncthreads();
    if (act) {
      const float* src = (task < 24) ? sm : sh;
      float* dstbuf = (task < 24) ? gil : ghl;
#pragma unroll
      for (int p = 0; p < 4; ++p) {
        int ln = 5 * p + slot;
        const float4* srow = (const float4*)(src + ln * SMP);
        float4 acc = {0.f, 0.f, 0.f, 0.f};
#pragma unroll
        for (int q = 0; q < 8; ++q) {
          float4 f = srow[q];
          float4 w0 = wcol[4 * q], w1 = wcol[4 * q + 1];
          float4 w2 = wcol[4 * q + 2], w3 = wcol[4 * q + 3];
          acc.x = fmaf(f.x, w0.x, acc.x); acc.y = fmaf(f.x, w0.y, acc.y);
          acc.z = fmaf(f.x, w0.z, acc.z); acc.w = fmaf(f.x, w0.w, acc.w);
          acc.x = fmaf(f.y, w1.x, acc.x); acc.y = fmaf(f.y, w1.y, acc.y);
          acc.z = fmaf(f.y, w1.z, acc.z); acc.w = fmaf(f.y, w1.w, acc.w);
          acc.x = fmaf(f.z, w2.x, acc.x); acc.y = fmaf(f.z, w2.y, acc.y);
          acc.z = fmaf(f.z, w2.z, acc.z); acc.w = fmaf(f.z, w2.w, acc.w);
          acc.x = fmaf(f.w, w3.x, acc.x); acc.y = fmaf(f.w, w3.y, acc.y);
          acc.z = fmaf(f.w, w3.z, acc.z); acc.w = fmaf(f.w, w3.w, acc.w);
        }
        *(float4*)(dstbuf + ln * 96 + c4) = acc;
      }
    }
    __syncthreads();
    for (int idx = t; idx < GNPB * 32; idx += 256) {
      int ln = idx >> 5, o = idx & 31;
      float gir = gil[ln * 96 + o]       + bih[o];
      float giz = gil[ln * 96 + 32 + o]  + bih[32 + o];
      float gin = gil[ln * 96 + 64 + o]  + bih[64 + o];
      float ghr = ghl[ln * 96 + o]       + bhh[o];
      float ghz = ghl[ln * 96 + 32 + o]  + bhh[32 + o];
      float ghn = ghl[ln * 96 + 64 + o]  + bhh[64 + o];
      float h = sh[ln * SMP + o];
      float r = 1.f / (1.f + expf(-(gir + ghr)));
      float z = 1.f / (1.f + expf(-(giz + ghz)));
      float nn = tanhf(fmaf(r, ghn, gin));
      feat[base32 + idx] = (1.f - z) * nn + z * h;
    }
    __syncthreads();
  }
}

// ---- global mean pool ----
__global__ __launch_bounds__(256) void k_pool(const float* __restrict__ feat,
                                              const int* __restrict__ batch,
                                              float* __restrict__ pooled,
                                              float* __restrict__ cnts) {
  int id = blockIdx.x * 256 + threadIdx.x;     // N*32
  int n = id >> 5, o = id & 31;
  int b = batch[n];
  unsafeAtomicAdd(&pooled[b * H + o], feat[id]);
  if (o == 0) unsafeAtomicAdd(&cnts[b], 1.f);
}

// ---- final head ----
__global__ __launch_bounds__(256) void k_final(const float* __restrict__ pooled,
                                               const float* __restrict__ cnts,
                                               const float* __restrict__ W1,
                                               const float* __restrict__ b1,
                                               float* __restrict__ y) {
  int gph = blockIdx.x * 256 + threadIdx.x;
  if (gph >= NG) return;
  float c = fmaxf(cnts[gph], 1.f);
  float acc = 0.f;
#pragma unroll
  for (int o = 0; o < H; ++o) acc = fmaf(pooled[gph * H + o], W1[o], acc);
  y[gph] = acc / c + b1[0];
}

extern "C" void kernel_launch(void* const* d_in, const int* in_sizes, int n_in,
                              void* d_out, int out_size, void* d_ws, size_t ws_size,
                              hipStream_t stream) {
  const float* x     = (const float*)d_in[0];
  const int*   ei    = (const int*)d_in[1];
  const float* ea    = (const float*)d_in[2];
  const int*   batch = (const int*)d_in[3];
  const float* W0    = (const float*)d_in[4];
  const float* b0    = (const float*)d_in[5];
  const float* We    = (const float*)d_in[6];
  const float* be    = (const float*)d_in[7];
  const float* Wroot = (const float*)d_in[8];
  const float* bconv = (const float*)d_in[9];
  const float* Wih   = (const float*)d_in[10];
  const float* bih   = (const float*)d_in[11];
  const float* Whh   = (const float*)d_in[12];
  const float* bhh   = (const float*)d_in[13];
  const float* W1    = (const float*)d_in[14];
  const float* b1    = (const float*)d_in[15];

  float* ws       = (float*)d_ws;
  float* feat     = ws;                         // 3,200,000
  float* agg      = ws + 3200000;               // 3,200,000
  float* pooled   = ws + 6400000;               // 65,536
  float* cnts     = ws + 6465536;               // 2,048
  float* ea_perm  = ws + 6467584;               // 6,400,000 (16B-aligned)
  int*   ibuf     = (int*)(ws + 12867584);
  int*   deg      = ibuf;                       // 100,000
  int*   rowptr   = ibuf + 100000;              // 100,001
  int*   nextp    = ibuf + 200004;              // 100,000
  int*   src_perm = ibuf + 300004;              // 400,000
  int*   dst_perm = ibuf + 700004;              // 400,000

  const int NB_NODE = (NN * H) / 256;           // 12500
  const int NB_E    = (NE + 255) / 256;         // 1563

  // one-time CSR build (iteration-invariant)
  hipMemsetAsync(deg, 0, NN * sizeof(int), stream);
  k_hist<<<NB_E, 256, 0, stream>>>(ei, deg);
  k_scan<<<1, 1024, 0, stream>>>(deg, rowptr, nextp);
  k_scatter<<<NB_E, 256, 0, stream>>>(ei, ea, nextp, src_perm, dst_perm, ea_perm);

  k_lin0<<<NB_NODE, 256, 0, stream>>>(x, W0, b0, feat);
  for (int it = 0; it < 3; ++it) {
    k_pre<<<NB_NODE, 256, 0, stream>>>(feat, Wroot, bconv, agg);
    k_fused<<<NN / NPB, 256, 0, stream>>>(feat, We, be, rowptr, src_perm, dst_perm,
                                          ea_perm, agg);
    k_gru2<<<768, 256, 0, stream>>>(agg, Wih, bih, Whh, bhh, feat);
  }
  hipMemsetAsync(pooled, 0, (size_t)(NG * H + NG) * 4, stream);
  k_pool<<<NB_NODE, 256, 0, stream>>>(feat, batch, pooled, cnts);
  k_final<<<(NG + 255) / 256, 256, 0, stream>>>(pooled, cnts, W1, b1, (float*)d_out);
}

// Round 6
// 664.187 us; speedup vs baseline: 3.1557x; 1.3188x over previous
//
#include <hip/hip_runtime.h>
#include <cstdint>

#define NN 100000
#define NE 400000
#define NG 2048
#define H  32
#define ED 16
#define NPB 16    // src-nodes per block in k_fused (100000 % 16 == 0 -> 6250 blocks)
#define GNPB 20   // nodes per group in k_gru2
#define SMP 36    // padded row stride for sm/sh in k_gru2
#define SCB 1024  // elements per scan block
#define NBL ((NN + SCB - 1) / SCB)   // 98

// ---------------- lin0: feat = relu(x @ W0^T + b0) ----------------
__global__ __launch_bounds__(256) void k_lin0(const float* __restrict__ x,
                                              const float* __restrict__ W0,
                                              const float* __restrict__ b0,
                                              float* __restrict__ feat) {
  __shared__ float w0t[1024];                  // W0^T[i][o]
  int t = threadIdx.x;
  for (int idx = t; idx < 1024; idx += 256) {
    int o = idx >> 5, i = idx & 31;
    w0t[(i << 5) | o] = W0[idx];
  }
  __syncthreads();
  int id = blockIdx.x * 256 + t;               // N*32 threads exactly
  int n = id >> 5, o = id & 31;
  const float* xr = x + n * H;
  float acc = b0[o];
#pragma unroll
  for (int i = 0; i < H; ++i) acc = fmaf(xr[i], w0t[(i << 5) | o], acc);
  feat[id] = fmaxf(acc, 0.f);
}

// ---- CSR build (once per launch): histogram, 3-stage scan, scatter ----
__global__ __launch_bounds__(256) void k_hist(const int* __restrict__ ei,
                                              int* __restrict__ deg) {
  int e = blockIdx.x * 256 + threadIdx.x;
  if (e < NE) atomicAdd(&deg[ei[e]], 1);
}

// stage 1: per-block sum of SCB degrees
__global__ __launch_bounds__(256) void k_bsum(const int* __restrict__ deg,
                                              int* __restrict__ bsum) {
  __shared__ int red[256];
  int b = blockIdx.x, t = threadIdx.x;
  int base = b * SCB;
  int s = 0;
#pragma unroll
  for (int k = 0; k < 4; ++k) {
    int i = base + k * 256 + t;
    if (i < NN) s += deg[i];
  }
  red[t] = s;
  __syncthreads();
  for (int off = 128; off > 0; off >>= 1) {
    if (t < off) red[t] += red[t + off];
    __syncthreads();
  }
  if (t == 0) bsum[b] = red[0];
}

// stage 2: exclusive scan of NBL block sums (single tiny block)
__global__ __launch_bounds__(128) void k_bscan(const int* __restrict__ bsum,
                                               int* __restrict__ boff,
                                               int* __restrict__ rowptr) {
  __shared__ int sh[128];
  int t = threadIdx.x;
  int v = (t < NBL) ? bsum[t] : 0;
  sh[t] = v;
  __syncthreads();
  for (int off = 1; off < 128; off <<= 1) {
    int u = (t >= off) ? sh[t - off] : 0;
    __syncthreads();
    sh[t] += u;
    __syncthreads();
  }
  if (t < NBL) boff[t] = sh[t] - v;            // exclusive
  if (t == 0) rowptr[NN] = NE;
}

// stage 3: per-block exclusive prefix, write rowptr & nextp
__global__ __launch_bounds__(256) void k_rowptr(const int* __restrict__ deg,
                                                const int* __restrict__ boff,
                                                int* __restrict__ rowptr,
                                                int* __restrict__ nextp) {
  __shared__ int sh[256];
  int b = blockIdx.x, t = threadIdx.x;
  int base = b * SCB + t * 4;
  int d0 = 0, d1 = 0, d2 = 0, d3 = 0;
  if (base + 0 < NN) d0 = deg[base + 0];
  if (base + 1 < NN) d1 = deg[base + 1];
  if (base + 2 < NN) d2 = deg[base + 2];
  if (base + 3 < NN) d3 = deg[base + 3];
  int ts = d0 + d1 + d2 + d3;
  sh[t] = ts;
  __syncthreads();
  for (int off = 1; off < 256; off <<= 1) {
    int u = (t >= off) ? sh[t - off] : 0;
    __syncthreads();
    sh[t] += u;
    __syncthreads();
  }
  int run = boff[b] + sh[t] - ts;              // exclusive prefix for this thread
  if (base + 0 < NN) { rowptr[base + 0] = run; nextp[base + 0] = run; run += d0; }
  if (base + 1 < NN) { rowptr[base + 1] = run; nextp[base + 1] = run; run += d1; }
  if (base + 2 < NN) { rowptr[base + 2] = run; nextp[base + 2] = run; run += d2; }
  if (base + 3 < NN) { rowptr[base + 3] = run; nextp[base + 3] = run; run += d3; }
}

__global__ __launch_bounds__(256) void k_scatter(const int* __restrict__ ei,
                                                 const float* __restrict__ ea,
                                                 int* __restrict__ nextp,
                                                 int* __restrict__ src_perm,
                                                 int* __restrict__ dst_perm,
                                                 float* __restrict__ ea_perm) {
  int e = blockIdx.x * 256 + threadIdx.x;
  if (e >= NE) return;
  int src = ei[e], dst = ei[NE + e];
  int p = atomicAdd(&nextp[src], 1);
  src_perm[p] = src;
  dst_perm[p] = dst;
  const float4* s4 = (const float4*)(ea + (size_t)e * ED);
  float4* d4 = (float4*)(ea_perm + (size_t)p * ED);
  d4[0] = s4[0]; d4[1] = s4[1]; d4[2] = s4[2]; d4[3] = s4[3];
}

// ---- per-iteration: agg init (root term + bconv) ----
__global__ __launch_bounds__(256) void k_pre(const float* __restrict__ feat,
                                             const float* __restrict__ Wroot,
                                             const float* __restrict__ bconv,
                                             float* __restrict__ agg) {
  __shared__ float wrt[1024];                  // Wroot^T[i][o]
  int t = threadIdx.x;
  for (int idx = t; idx < 1024; idx += 256) {
    int o = idx >> 5, i = idx & 31;
    wrt[(i << 5) | o] = Wroot[idx];
  }
  __syncthreads();
  int id = blockIdx.x * 256 + t;               // N*32
  int n = id >> 5, o = id & 31;
  const float* fr = feat + n * H;
  float a = bconv[o];
#pragma unroll
  for (int i = 0; i < H; ++i) a = fmaf(fr[i], wrt[(i << 5) | o], a);
  agg[id] = a;
}

// ---- fused g+edge: low-VGPR, conflict-free LDS, one src-group per block ----
// sg layout: logical float4-slot s of row ln stored at phys slot (s&3)*32+(s>>2).
__global__ __launch_bounds__(256) void k_fused(const float* __restrict__ feat,
                                               const float* __restrict__ We,
                                               const float* __restrict__ be,
                                               const int* __restrict__ rowptr,
                                               const int* __restrict__ src_perm,
                                               const int* __restrict__ dst_perm,
                                               const float* __restrict__ ea_perm,
                                               float* __restrict__ agg) {
  __shared__ float sf[NPB * 32];               // 2 KB
  __shared__ float snb[NPB * 32];              // 2 KB
  __shared__ float sg[NPB * 512];              // 32 KB
  __shared__ float sbe[1024];                  // 4 KB
  int t = threadIdx.x;
  int base = blockIdx.x * NPB;                 // grid = NN/NPB = 6250

  for (int idx = t; idx < NPB * 32; idx += 256) sf[idx] = feat[base * 32 + idx];
  for (int idx = t; idx < 1024; idx += 256) sbe[idx] = be[idx];
  __syncthreads();

  // nodeb[ln][o] = sum_i sf[ln][i] * be[i*32+o]
  {
    int o = t & 31;
    for (int ln = t >> 5; ln < NPB; ln += 8) {
      float nb = 0.f;
#pragma unroll
      for (int i = 0; i < 32; ++i) nb = fmaf(sf[ln * 32 + i], sbe[(i << 5) | o], nb);
      snb[ln * 32 + o] = nb;
    }
  }
  // g rows: thread = column cj for 8 nodes; We streamed from L2
  {
    int cj = t & 127, nh = t >> 7;
    const float4* We4 = (const float4*)We;     // [32][128] float4
    float4 acc[8];
#pragma unroll
    for (int j = 0; j < 8; ++j) acc[j] = make_float4(0.f, 0.f, 0.f, 0.f);
    for (int i = 0; i < 32; ++i) {
      float4 w = We4[i * 128 + cj];
#pragma unroll
      for (int j = 0; j < 8; ++j) {
        float fi = sf[(nh * 8 + j) * 32 + i];
        acc[j].x = fmaf(fi, w.x, acc[j].x);
        acc[j].y = fmaf(fi, w.y, acc[j].y);
        acc[j].z = fmaf(fi, w.z, acc[j].z);
        acc[j].w = fmaf(fi, w.w, acc[j].w);
      }
    }
    float4* sg4 = (float4*)sg;
    int pslot = (cj & 3) * 32 + (cj >> 2);
#pragma unroll
    for (int j = 0; j < 8; ++j) sg4[(nh * 8 + j) * 128 + pslot] = acc[j];
  }
  __syncthreads();

  // edges of this group: contiguous [rowptr[base], rowptr[base+NPB])
  int e0 = rowptr[base], e1 = rowptr[base + NPB];
  int o = t & 31, slot = t >> 5;
  const float4* sg4 = (const float4*)sg;
  for (int e = e0 + slot; e < e1; e += 8) {
    int src = src_perm[e];
    int dst = dst_perm[e];
    int ln = src - base;
    const float4* e4 = (const float4*)(ea_perm + (size_t)e * ED);
    float acc = snb[ln * 32 + o];
#pragma unroll
    for (int q = 0; q < 4; ++q) {
      float4 gv = sg4[ln * 128 + q * 32 + o];
      float4 ev = e4[q];
      acc = fmaf(ev.x, gv.x, acc);
      acc = fmaf(ev.y, gv.y, acc);
      acc = fmaf(ev.z, gv.z, acc);
      acc = fmaf(ev.w, gv.w, acc);
    }
    unsafeAtomicAdd(&agg[(size_t)dst * 32 + o], acc);
  }
}

// ---- fused GRU: gi = relu(agg)@Wih^T, gh = h@Whh^T, then gates ----
__global__ __launch_bounds__(256) void k_gru2(const float* __restrict__ agg,
                                              const float* __restrict__ Wih,
                                              const float* __restrict__ bih,
                                              const float* __restrict__ Whh,
                                              const float* __restrict__ bhh,
                                              float* __restrict__ feat) {
  __shared__ float wsw[6144];                  // XOR-swizzled [m][r][i^(r&31)]
  __shared__ float sm[GNPB * SMP];
  __shared__ float sh[GNPB * SMP];
  __shared__ float gil[GNPB * 96];
  __shared__ float ghl[GNPB * 96];
  int t = threadIdx.x;

  for (int idx = t; idx < 3072; idx += 256) {
    int r = idx >> 5, i = idx & 31;
    int sw = (r << 5) | (i ^ (r & 31));
    wsw[sw]        = Wih[idx];
    wsw[3072 + sw] = Whh[idx];
  }
  __syncthreads();

  int task = t / 5;
  int slot = t - task * 5;
  bool act = task < 48;
  int c4 = (act ? (task < 24 ? task : task - 24) : 0) * 4;
  int mbase = (task < 24) ? 0 : 3072;
  float4 wcol[32];
  if (act) {
#pragma unroll
    for (int i = 0; i < 32; ++i) {
      wcol[i].x = wsw[mbase + ((c4 + 0) << 5) + (i ^ ((c4 + 0) & 31))];
      wcol[i].y = wsw[mbase + ((c4 + 1) << 5) + (i ^ ((c4 + 1) & 31))];
      wcol[i].z = wsw[mbase + ((c4 + 2) << 5) + (i ^ ((c4 + 2) & 31))];
      wcol[i].w = wsw[mbase + ((c4 + 3) << 5) + (i ^ ((c4 + 3) & 31))];
    }
  }

  for (int g0 = blockIdx.x; g0 < NN / GNPB; g0 += gridDim.x) {
    size_t base32 = (size_t)g0 * GNPB * 32;
    for (int idx = t; idx < GNPB * 32; idx += 256) {
      int ln = idx >> 5, i = idx & 31;
      sm[ln * SMP + i] = fmaxf(agg[base32 + idx], 0.f);
      sh[ln * SMP + i] = feat[base32 + idx];
    }
    __syncthreads();
    if (act) {
      const float* src = (task < 24) ? sm : sh;
      float* dstbuf = (task < 24) ? gil : ghl;
#pragma unroll
      for (int p = 0; p < 4; ++p) {
        int ln = 5 * p + slot;
        const float4* srow = (const float4*)(src + ln * SMP);
        float4 acc = {0.f, 0.f, 0.f, 0.f};
#pragma unroll
        for (int q = 0; q < 8; ++q) {
          float4 f = srow[q];
          float4 w0 = wcol[4 * q], w1 = wcol[4 * q + 1];
          float4 w2 = wcol[4 * q + 2], w3 = wcol[4 * q + 3];
          acc.x = fmaf(f.x, w0.x, acc.x); acc.y = fmaf(f.x, w0.y, acc.y);
          acc.z = fmaf(f.x, w0.z, acc.z); acc.w = fmaf(f.x, w0.w, acc.w);
          acc.x = fmaf(f.y, w1.x, acc.x); acc.y = fmaf(f.y, w1.y, acc.y);
          acc.z = fmaf(f.y, w1.z, acc.z); acc.w = fmaf(f.y, w1.w, acc.w);
          acc.x = fmaf(f.z, w2.x, acc.x); acc.y = fmaf(f.z, w2.y, acc.y);
          acc.z = fmaf(f.z, w2.z, acc.z); acc.w = fmaf(f.z, w2.w, acc.w);
          acc.x = fmaf(f.w, w3.x, acc.x); acc.y = fmaf(f.w, w3.y, acc.y);
          acc.z = fmaf(f.w, w3.z, acc.z); acc.w = fmaf(f.w, w3.w, acc.w);
        }
        *(float4*)(dstbuf + ln * 96 + c4) = acc;
      }
    }
    __syncthreads();
    for (int idx = t; idx < GNPB * 32; idx += 256) {
      int ln = idx >> 5, o = idx & 31;
      float gir = gil[ln * 96 + o]       + bih[o];
      float giz = gil[ln * 96 + 32 + o]  + bih[32 + o];
      float gin = gil[ln * 96 + 64 + o]  + bih[64 + o];
      float ghr = ghl[ln * 96 + o]       + bhh[o];
      float ghz = ghl[ln * 96 + 32 + o]  + bhh[32 + o];
      float ghn = ghl[ln * 96 + 64 + o]  + bhh[64 + o];
      float h = sh[ln * SMP + o];
      float r = 1.f / (1.f + expf(-(gir + ghr)));
      float z = 1.f / (1.f + expf(-(giz + ghz)));
      float nn = tanhf(fmaf(r, ghn, gin));
      feat[base32 + idx] = (1.f - z) * nn + z * h;
    }
    __syncthreads();
  }
}

// ---- global mean pool ----
__global__ __launch_bounds__(256) void k_pool(const float* __restrict__ feat,
                                              const int* __restrict__ batch,
                                              float* __restrict__ pooled,
                                              float* __restrict__ cnts) {
  int id = blockIdx.x * 256 + threadIdx.x;     // N*32
  int n = id >> 5, o = id & 31;
  int b = batch[n];
  unsafeAtomicAdd(&pooled[b * H + o], feat[id]);
  if (o == 0) unsafeAtomicAdd(&cnts[b], 1.f);
}

// ---- final head ----
__global__ __launch_bounds__(256) void k_final(const float* __restrict__ pooled,
                                               const float* __restrict__ cnts,
                                               const float* __restrict__ W1,
                                               const float* __restrict__ b1,
                                               float* __restrict__ y) {
  int gph = blockIdx.x * 256 + threadIdx.x;
  if (gph >= NG) return;
  float c = fmaxf(cnts[gph], 1.f);
  float acc = 0.f;
#pragma unroll
  for (int o = 0; o < H; ++o) acc = fmaf(pooled[gph * H + o], W1[o], acc);
  y[gph] = acc / c + b1[0];
}

extern "C" void kernel_launch(void* const* d_in, const int* in_sizes, int n_in,
                              void* d_out, int out_size, void* d_ws, size_t ws_size,
                              hipStream_t stream) {
  const float* x     = (const float*)d_in[0];
  const int*   ei    = (const int*)d_in[1];
  const float* ea    = (const float*)d_in[2];
  const int*   batch = (const int*)d_in[3];
  const float* W0    = (const float*)d_in[4];
  const float* b0    = (const float*)d_in[5];
  const float* We    = (const float*)d_in[6];
  const float* be    = (const float*)d_in[7];
  const float* Wroot = (const float*)d_in[8];
  const float* bconv = (const float*)d_in[9];
  const float* Wih   = (const float*)d_in[10];
  const float* bih   = (const float*)d_in[11];
  const float* Whh   = (const float*)d_in[12];
  const float* bhh   = (const float*)d_in[13];
  const float* W1    = (const float*)d_in[14];
  const float* b1    = (const float*)d_in[15];

  float* ws       = (float*)d_ws;
  float* feat     = ws;                         // 3,200,000
  float* agg      = ws + 3200000;               // 3,200,000
  float* pooled   = ws + 6400000;               // 65,536
  float* cnts     = ws + 6465536;               // 2,048
  float* ea_perm  = ws + 6467584;               // 6,400,000 (16B-aligned)
  int*   ibuf     = (int*)(ws + 12867584);
  int*   deg      = ibuf;                       // 100,000
  int*   rowptr   = ibuf + 100000;              // 100,001
  int*   nextp    = ibuf + 200004;              // 100,000
  int*   src_perm = ibuf + 300004;              // 400,000
  int*   dst_perm = ibuf + 700004;              // 400,000
  int*   bsum     = ibuf + 1100004;             // 98
  int*   boff     = ibuf + 1100104;             // 98

  const int NB_NODE = (NN * H) / 256;           // 12500
  const int NB_E    = (NE + 255) / 256;         // 1563

  // one-time CSR build (iteration-invariant)
  hipMemsetAsync(deg, 0, NN * sizeof(int), stream);
  k_hist<<<NB_E, 256, 0, stream>>>(ei, deg);
  k_bsum<<<NBL, 256, 0, stream>>>(deg, bsum);
  k_bscan<<<1, 128, 0, stream>>>(bsum, boff, rowptr);
  k_rowptr<<<NBL, 256, 0, stream>>>(deg, boff, rowptr, nextp);
  k_scatter<<<NB_E, 256, 0, stream>>>(ei, ea, nextp, src_perm, dst_perm, ea_perm);

  k_lin0<<<NB_NODE, 256, 0, stream>>>(x, W0, b0, feat);
  for (int it = 0; it < 3; ++it) {
    k_pre<<<NB_NODE, 256, 0, stream>>>(feat, Wroot, bconv, agg);
    k_fused<<<NN / NPB, 256, 0, stream>>>(feat, We, be, rowptr, src_perm, dst_perm,
                                          ea_perm, agg);
    k_gru2<<<768, 256, 0, stream>>>(agg, Wih, bih, Whh, bhh, feat);
  }
  hipMemsetAsync(pooled, 0, (size_t)(NG * H + NG) * 4, stream);
  k_pool<<<NB_NODE, 256, 0, stream>>>(feat, batch, pooled, cnts);
  k_final<<<(NG + 255) / 256, 256, 0, stream>>>(pooled, cnts, W1, b1, (float*)d_out);
}

// Round 8
// 632.887 us; speedup vs baseline: 3.3118x; 1.0495x over previous
//
#include <hip/hip_runtime.h>
#include <cstdint>

#define NN 100000
#define NE 400000
#define NG 2048
#define H  32
#define ED 16
#define NPB 16    // nodes per block in k_fused / k_gru3 (100000/16 = 6250)
#define SCB 1024
#define NBL ((NN + SCB - 1) / SCB)   // 98

__device__ __forceinline__ void fma4(float4& a, float s, const float4& w) {
  a.x = fmaf(s, w.x, a.x);
  a.y = fmaf(s, w.y, a.y);
  a.z = fmaf(s, w.z, a.z);
  a.w = fmaf(s, w.w, a.w);
}

// ---------------- lin0: feat = relu(x @ W0^T + b0) ----------------
__global__ __launch_bounds__(256) void k_lin0(const float* __restrict__ x,
                                              const float* __restrict__ W0,
                                              const float* __restrict__ b0,
                                              float* __restrict__ feat) {
  __shared__ float w0t[1024];
  int t = threadIdx.x;
  for (int idx = t; idx < 1024; idx += 256) {
    int o = idx >> 5, i = idx & 31;
    w0t[(i << 5) | o] = W0[idx];
  }
  __syncthreads();
  int id = blockIdx.x * 256 + t;
  int n = id >> 5, o = id & 31;
  const float* xr = x + n * H;
  float acc = b0[o];
#pragma unroll
  for (int i = 0; i < H; ++i) acc = fmaf(xr[i], w0t[(i << 5) | o], acc);
  feat[id] = fmaxf(acc, 0.f);
}

// ---- CSR build ----
__global__ __launch_bounds__(256) void k_hist(const int* __restrict__ ei,
                                              int* __restrict__ deg) {
  int e = blockIdx.x * 256 + threadIdx.x;
  if (e < NE) atomicAdd(&deg[ei[e]], 1);
}

__global__ __launch_bounds__(256) void k_bsum(const int* __restrict__ deg,
                                              int* __restrict__ bsum) {
  __shared__ int red[256];
  int b = blockIdx.x, t = threadIdx.x;
  int base = b * SCB;
  int s = 0;
#pragma unroll
  for (int k = 0; k < 4; ++k) {
    int i = base + k * 256 + t;
    if (i < NN) s += deg[i];
  }
  red[t] = s;
  __syncthreads();
  for (int off = 128; off > 0; off >>= 1) {
    if (t < off) red[t] += red[t + off];
    __syncthreads();
  }
  if (t == 0) bsum[b] = red[0];
}

__global__ __launch_bounds__(128) void k_bscan(const int* __restrict__ bsum,
                                               int* __restrict__ boff,
                                               int* __restrict__ rowptr) {
  __shared__ int sh[128];
  int t = threadIdx.x;
  int v = (t < NBL) ? bsum[t] : 0;
  sh[t] = v;
  __syncthreads();
  for (int off = 1; off < 128; off <<= 1) {
    int u = (t >= off) ? sh[t - off] : 0;
    __syncthreads();
    sh[t] += u;
    __syncthreads();
  }
  if (t < NBL) boff[t] = sh[t] - v;
  if (t == 0) rowptr[NN] = NE;
}

__global__ __launch_bounds__(256) void k_rowptr(const int* __restrict__ deg,
                                                const int* __restrict__ boff,
                                                int* __restrict__ rowptr,
                                                int* __restrict__ nextp) {
  __shared__ int sh[256];
  int b = blockIdx.x, t = threadIdx.x;
  int base = b * SCB + t * 4;
  int d0 = 0, d1 = 0, d2 = 0, d3 = 0;
  if (base + 0 < NN) d0 = deg[base + 0];
  if (base + 1 < NN) d1 = deg[base + 1];
  if (base + 2 < NN) d2 = deg[base + 2];
  if (base + 3 < NN) d3 = deg[base + 3];
  int ts = d0 + d1 + d2 + d3;
  sh[t] = ts;
  __syncthreads();
  for (int off = 1; off < 256; off <<= 1) {
    int u = (t >= off) ? sh[t - off] : 0;
    __syncthreads();
    sh[t] += u;
    __syncthreads();
  }
  int run = boff[b] + sh[t] - ts;
  if (base + 0 < NN) { rowptr[base + 0] = run; nextp[base + 0] = run; run += d0; }
  if (base + 1 < NN) { rowptr[base + 1] = run; nextp[base + 1] = run; run += d1; }
  if (base + 2 < NN) { rowptr[base + 2] = run; nextp[base + 2] = run; run += d2; }
  if (base + 3 < NN) { rowptr[base + 3] = run; nextp[base + 3] = run; run += d3; }
}

__global__ __launch_bounds__(256) void k_scatter(const int* __restrict__ ei,
                                                 const float* __restrict__ ea,
                                                 int* __restrict__ nextp,
                                                 int* __restrict__ src_perm,
                                                 int* __restrict__ dst_perm,
                                                 float* __restrict__ ea_perm) {
  int e = blockIdx.x * 256 + threadIdx.x;
  if (e >= NE) return;
  int src = ei[e], dst = ei[NE + e];
  int p = atomicAdd(&nextp[src], 1);
  src_perm[p] = src;
  dst_perm[p] = dst;
  const float4* s4 = (const float4*)(ea + (size_t)e * ED);
  float4* d4 = (float4*)(ea_perm + (size_t)p * ED);
  d4[0] = s4[0]; d4[1] = s4[1]; d4[2] = s4[2]; d4[3] = s4[3];
}

// ---- weight pre-transpose (once): wcomb[i][192] = [WihT | WhhT], wrbe[i][64] = [WrootT | be] ----
__global__ __launch_bounds__(256) void k_prep(const float* __restrict__ Wih,
                                              const float* __restrict__ Whh,
                                              const float* __restrict__ Wroot,
                                              const float* __restrict__ be,
                                              float* __restrict__ wcomb,
                                              float* __restrict__ wrbe) {
  int idx = blockIdx.x * 256 + threadIdx.x;
  if (idx < 6144) {
    int i = idx / 192, o = idx % 192;
    wcomb[idx] = (o < 96) ? Wih[o * 32 + i] : Whh[(o - 96) * 32 + i];
  } else if (idx < 8192) {
    int r = idx - 6144;
    int i = r / 64, c = r % 64;
    wrbe[r] = (c < 32) ? Wroot[c * 32 + i] : be[i * 32 + (c - 32)];
  }
}

// ---- one-time agg/nodeb init before iteration 0 ----
__global__ __launch_bounds__(256) void k_pre_nb(const float* __restrict__ feat,
                                                const float* __restrict__ Wroot,
                                                const float* __restrict__ bconv,
                                                const float* __restrict__ be,
                                                float* __restrict__ agg,
                                                float* __restrict__ nodeb) {
  __shared__ float wrt[1024];
  int t = threadIdx.x;
  for (int idx = t; idx < 1024; idx += 256) {
    int o = idx >> 5, i = idx & 31;
    wrt[(i << 5) | o] = Wroot[idx];
  }
  __syncthreads();
  int id = blockIdx.x * 256 + t;
  int n = id >> 5, o = id & 31;
  const float* fr = feat + n * H;
  float a = bconv[o];
  float nb = 0.f;
#pragma unroll
  for (int i = 0; i < H; ++i) {
    float f = fr[i];
    a  = fmaf(f, wrt[(i << 5) | o], a);
    nb = fmaf(f, be[(i << 5) | o], nb);
  }
  agg[id]   = a;
  nodeb[id] = nb;
}

// ---- fused g+edge v3: conflict-free sg both sides, f4 LDS reads ----
// Thread (cj) computes LOGICAL f4-slot s' = 4*(cj&31)+(cj>>5) and stores at
// PHYS slot cj (consecutive across lanes -> conflict-free write). Edge read
// at phys q*32+o (consecutive) yields logical o*4+q as required.
__global__ __launch_bounds__(256) void k_fused(const float* __restrict__ feat,
                                               const float* __restrict__ We,
                                               const float* __restrict__ nodeb_g,
                                               const int* __restrict__ rowptr,
                                               const int* __restrict__ src_perm,
                                               const int* __restrict__ dst_perm,
                                               const float* __restrict__ ea_perm,
                                               float* __restrict__ agg) {
  __shared__ float4 sf4[NPB * 8];              // 2 KB
  __shared__ float  snb[NPB * 32];             // 2 KB
  __shared__ float4 sg4[NPB * 128];            // 32 KB
  int t = threadIdx.x;
  int base = blockIdx.x * NPB;

  if (t < 128) sf4[t] = ((const float4*)feat)[base * 8 + t];
  snb[t]       = nodeb_g[base * 32 + t];
  snb[t + 256] = nodeb_g[base * 32 + t + 256];
  __syncthreads();

  // g phase
  {
    int cj = t & 127, nh = t >> 7;
    int sp = 4 * (cj & 31) + (cj >> 5);        // logical slot this thread owns
    const float4* We4 = (const float4*)We;     // [32][128]
    float4 acc[8];
#pragma unroll
    for (int j = 0; j < 8; ++j) acc[j] = make_float4(0.f, 0.f, 0.f, 0.f);
#pragma unroll
    for (int i4 = 0; i4 < 8; ++i4) {
      float4 w0 = We4[(4 * i4 + 0) * 128 + sp];
      float4 w1 = We4[(4 * i4 + 1) * 128 + sp];
      float4 w2 = We4[(4 * i4 + 2) * 128 + sp];
      float4 w3 = We4[(4 * i4 + 3) * 128 + sp];
#pragma unroll
      for (int j = 0; j < 8; ++j) {
        float4 f = sf4[(nh * 8 + j) * 8 + i4];
        fma4(acc[j], f.x, w0);
        fma4(acc[j], f.y, w1);
        fma4(acc[j], f.z, w2);
        fma4(acc[j], f.w, w3);
      }
    }
#pragma unroll
    for (int j = 0; j < 8; ++j) sg4[(nh * 8 + j) * 128 + cj] = acc[j];
  }
  __syncthreads();

  // edge phase
  int e0 = rowptr[base], e1 = rowptr[base + NPB];
  int o = t & 31, slot = t >> 5;
  for (int e = e0 + slot; e < e1; e += 8) {
    int src = src_perm[e];
    int dst = dst_perm[e];
    int ln = src - base;
    const float4* e4 = (const float4*)(ea_perm + (size_t)e * ED);
    float acc = snb[ln * 32 + o];
#pragma unroll
    for (int q = 0; q < 4; ++q) {
      float4 gv = sg4[ln * 128 + q * 32 + o];
      float4 ev = e4[q];
      acc = fmaf(ev.x, gv.x, acc);
      acc = fmaf(ev.y, gv.y, acc);
      acc = fmaf(ev.z, gv.z, acc);
      acc = fmaf(ev.w, gv.w, acc);
    }
    unsafeAtomicAdd(&agg[(size_t)dst * 32 + o], acc);
  }
}

// ---- gru3: gates GEMM (lane=col, node-broadcast) + fused Wroot/be epilogue ----
__global__ __launch_bounds__(256) void k_gru3(float* __restrict__ agg,
                                              float* __restrict__ feat,
                                              const float* __restrict__ wcomb,
                                              const float* __restrict__ wrbe,
                                              const float* __restrict__ bih,
                                              const float* __restrict__ bhh,
                                              const float* __restrict__ bconv,
                                              float* __restrict__ nodeb,
                                              int do_pre) {
  __shared__ float4 wlds[1536];                // [32][48] f4 = 24 KB
  __shared__ float4 wrl[512];                  // [32][16] f4 = 8 KB
  __shared__ float4 sm4[NPB * 8];              // m = relu(agg)
  __shared__ float4 sh4[NPB * 8];              // h_old
  __shared__ float4 shn4[NPB * 8];             // h_new
  __shared__ float4 gl4[NPB * 48];             // [16][48] f4 = 12 KB
  int t = threadIdx.x;
  int base = blockIdx.x * NPB;

  for (int idx = t; idx < 1536; idx += 256) wlds[idx] = ((const float4*)wcomb)[idx];
  for (int idx = t; idx < 512; idx += 256)  wrl[idx]  = ((const float4*)wrbe)[idx];
  if (t < 128) {
    float4 a = ((const float4*)agg)[base * 8 + t];
    a.x = fmaxf(a.x, 0.f); a.y = fmaxf(a.y, 0.f);
    a.z = fmaxf(a.z, 0.f); a.w = fmaxf(a.w, 0.f);
    sm4[t] = a;
    sh4[t] = ((const float4*)feat)[base * 8 + t];
  }
  __syncthreads();

  int wv = t >> 6, lane = t & 63;
  int ln0 = wv * 4;                            // 4 nodes per wave

  // phase A: gi/gh GEMM. lane<24: gi col=lane (input m); 24..47: gh col (input h)
  if (lane < 48) {
    const float4* S4 = (lane < 24) ? sm4 : sh4;
    float4 a0 = make_float4(0.f,0.f,0.f,0.f), a1 = a0, a2 = a0, a3 = a0;
#pragma unroll
    for (int i4 = 0; i4 < 8; ++i4) {
      float4 w0 = wlds[(4 * i4 + 0) * 48 + lane];
      float4 w1 = wlds[(4 * i4 + 1) * 48 + lane];
      float4 w2 = wlds[(4 * i4 + 2) * 48 + lane];
      float4 w3 = wlds[(4 * i4 + 3) * 48 + lane];
      float4 f0 = S4[(ln0 + 0) * 8 + i4];
      float4 f1 = S4[(ln0 + 1) * 8 + i4];
      float4 f2 = S4[(ln0 + 2) * 8 + i4];
      float4 f3 = S4[(ln0 + 3) * 8 + i4];
      fma4(a0, f0.x, w0); fma4(a0, f0.y, w1); fma4(a0, f0.z, w2); fma4(a0, f0.w, w3);
      fma4(a1, f1.x, w0); fma4(a1, f1.y, w1); fma4(a1, f1.z, w2); fma4(a1, f1.w, w3);
      fma4(a2, f2.x, w0); fma4(a2, f2.y, w1); fma4(a2, f2.z, w2); fma4(a2, f2.w, w3);
      fma4(a3, f3.x, w0); fma4(a3, f3.y, w1); fma4(a3, f3.z, w2); fma4(a3, f3.w, w3);
    }
    gl4[(ln0 + 0) * 48 + lane] = a0;
    gl4[(ln0 + 1) * 48 + lane] = a1;
    gl4[(ln0 + 2) * 48 + lane] = a2;
    gl4[(ln0 + 3) * 48 + lane] = a3;
  }
  __syncthreads();

  // phase B: gates elementwise (128 f4-items), write h_new
  if (t < 128) {
    int ln = t >> 3, o4 = t & 7;
    const float4* Bi = (const float4*)bih;
    const float4* Bh = (const float4*)bhh;
    float4 ir = gl4[ln * 48 + o4],       bi0 = Bi[o4];
    float4 iz = gl4[ln * 48 + 8 + o4],   bi1 = Bi[8 + o4];
    float4 in_ = gl4[ln * 48 + 16 + o4], bi2 = Bi[16 + o4];
    float4 hr = gl4[ln * 48 + 24 + o4],  bh0 = Bh[o4];
    float4 hz = gl4[ln * 48 + 32 + o4],  bh1 = Bh[8 + o4];
    float4 hn = gl4[ln * 48 + 40 + o4],  bh2 = Bh[16 + o4];
    float4 h = sh4[ln * 8 + o4];
    float4 out;
#define GATE(c) { \
    float grv = 1.f / (1.f + expf(-((ir.c + bi0.c) + (hr.c + bh0.c)))); \
    float gzv = 1.f / (1.f + expf(-((iz.c + bi1.c) + (hz.c + bh1.c)))); \
    float gnv = tanhf((in_.c + bi2.c) + grv * (hn.c + bh2.c)); \
    out.c = (1.f - gzv) * gnv + gzv * h.c; }
    GATE(x) GATE(y) GATE(z) GATE(w)
#undef GATE
    shn4[ln * 8 + o4] = out;
    ((float4*)feat)[base * 8 + t] = out;
  }
  __syncthreads();

  // phase C: agg_init = h_new @ WrootT + bconv ; nodeb = h_new @ be-matrix
  if (do_pre) {
    int col = lane & 15, nsub = lane >> 4;
    int ln = ln0 + nsub;
    float4 acc = make_float4(0.f, 0.f, 0.f, 0.f);
#pragma unroll
    for (int i4 = 0; i4 < 8; ++i4) {
      float4 f  = shn4[ln * 8 + i4];
      float4 w0 = wrl[(4 * i4 + 0) * 16 + col];
      float4 w1 = wrl[(4 * i4 + 1) * 16 + col];
      float4 w2 = wrl[(4 * i4 + 2) * 16 + col];
      float4 w3 = wrl[(4 * i4 + 3) * 16 + col];
      fma4(acc, f.x, w0); fma4(acc, f.y, w1); fma4(acc, f.z, w2); fma4(acc, f.w, w3);
    }
    if (col < 8) {
      float4 bc = ((const float4*)bconv)[col];
      acc.x += bc.x; acc.y += bc.y; acc.z += bc.z; acc.w += bc.w;
      ((float4*)agg)[(base + ln) * 8 + col] = acc;
    } else {
      ((float4*)nodeb)[(base + ln) * 8 + (col - 8)] = acc;
    }
  }
}

// ---- global mean pool ----
__global__ __launch_bounds__(256) void k_pool(const float* __restrict__ feat,
                                              const int* __restrict__ batch,
                                              float* __restrict__ pooled,
                                              float* __restrict__ cnts) {
  int id = blockIdx.x * 256 + threadIdx.x;
  int n = id >> 5, o = id & 31;
  int b = batch[n];
  unsafeAtomicAdd(&pooled[b * H + o], feat[id]);
  if (o == 0) unsafeAtomicAdd(&cnts[b], 1.f);
}

// ---- final head ----
__global__ __launch_bounds__(256) void k_final(const float* __restrict__ pooled,
                                               const float* __restrict__ cnts,
                                               const float* __restrict__ W1,
                                               const float* __restrict__ b1,
                                               float* __restrict__ y) {
  int gph = blockIdx.x * 256 + threadIdx.x;
  if (gph >= NG) return;
  float c = fmaxf(cnts[gph], 1.f);
  float acc = 0.f;
#pragma unroll
  for (int o = 0; o < H; ++o) acc = fmaf(pooled[gph * H + o], W1[o], acc);
  y[gph] = acc / c + b1[0];
}

extern "C" void kernel_launch(void* const* d_in, const int* in_sizes, int n_in,
                              void* d_out, int out_size, void* d_ws, size_t ws_size,
                              hipStream_t stream) {
  const float* x     = (const float*)d_in[0];
  const int*   ei    = (const int*)d_in[1];
  const float* ea    = (const float*)d_in[2];
  const int*   batch = (const int*)d_in[3];
  const float* W0    = (const float*)d_in[4];
  const float* b0    = (const float*)d_in[5];
  const float* We    = (const float*)d_in[6];
  const float* be    = (const float*)d_in[7];
  const float* Wroot = (const float*)d_in[8];
  const float* bconv = (const float*)d_in[9];
  const float* Wih   = (const float*)d_in[10];
  const float* bih   = (const float*)d_in[11];
  const float* Whh   = (const float*)d_in[12];
  const float* bhh   = (const float*)d_in[13];
  const float* W1    = (const float*)d_in[14];
  const float* b1    = (const float*)d_in[15];

  float* ws       = (float*)d_ws;
  float* feat     = ws;                         // 3,200,000
  float* agg      = ws + 3200000;               // 3,200,000
  float* nodeb    = ws + 6400000;               // 3,200,000
  float* pooled   = ws + 9600000;               // 65,536
  float* cnts     = ws + 9665536;               // 2,048
  float* wcomb    = ws + 9667584;               // 6,144
  float* wrbe     = ws + 9673728;               // 2,048
  float* ea_perm  = ws + 9675776;               // 6,400,000 (16B aligned)
  int*   ibuf     = (int*)(ws + 16075776);
  int*   deg      = ibuf;                       // 100,000
  int*   rowptr   = ibuf + 100000;              // 100,001
  int*   nextp    = ibuf + 200004;              // 100,000
  int*   src_perm = ibuf + 300004;              // 400,000
  int*   dst_perm = ibuf + 700004;              // 400,000
  int*   bsum     = ibuf + 1100004;             // 98
  int*   boff     = ibuf + 1100104;             // 98

  const int NB_NODE = (NN * H) / 256;           // 12500
  const int NB_E    = (NE + 255) / 256;         // 1563

  // one-time CSR build + weight transpose
  hipMemsetAsync(deg, 0, NN * sizeof(int), stream);
  k_hist<<<NB_E, 256, 0, stream>>>(ei, deg);
  k_bsum<<<NBL, 256, 0, stream>>>(deg, bsum);
  k_bscan<<<1, 128, 0, stream>>>(bsum, boff, rowptr);
  k_rowptr<<<NBL, 256, 0, stream>>>(deg, boff, rowptr, nextp);
  k_scatter<<<NB_E, 256, 0, stream>>>(ei, ea, nextp, src_perm, dst_perm, ea_perm);
  k_prep<<<32, 256, 0, stream>>>(Wih, Whh, Wroot, be, wcomb, wrbe);

  k_lin0<<<NB_NODE, 256, 0, stream>>>(x, W0, b0, feat);
  k_pre_nb<<<NB_NODE, 256, 0, stream>>>(feat, Wroot, bconv, be, agg, nodeb);
  for (int it = 0; it < 3; ++it) {
    k_fused<<<NN / NPB, 256, 0, stream>>>(feat, We, nodeb, rowptr, src_perm,
                                          dst_perm, ea_perm, agg);
    k_gru3<<<NN / NPB, 256, 0, stream>>>(agg, feat, wcomb, wrbe, bih, bhh, bconv,
                                         nodeb, it < 2 ? 1 : 0);
  }
  hipMemsetAsync(pooled, 0, (size_t)(NG * H + NG) * 4, stream);
  k_pool<<<NB_NODE, 256, 0, stream>>>(feat, batch, pooled, cnts);
  k_final<<<(NG + 255) / 256, 256, 0, stream>>>(pooled, cnts, W1, b1, (float*)d_out);
}

// Round 9
// 601.829 us; speedup vs baseline: 3.4827x; 1.0516x over previous
//
#include <hip/hip_runtime.h>
#include <cstdint>

#define NN 100000
#define NE 400000
#define NG 2048
#define H  32
#define ED 16
#define NPB 16    // nodes per block in k_fused / k_gru3 (100000/16 = 6250)
#define SCB 1024
#define NBL ((NN + SCB - 1) / SCB)   // 98

__device__ __forceinline__ void fma4(float4& a, float s, const float4& w) {
  a.x = fmaf(s, w.x, a.x);
  a.y = fmaf(s, w.y, a.y);
  a.z = fmaf(s, w.z, a.z);
  a.w = fmaf(s, w.w, a.w);
}

// ---------------- lin0: feat = relu(x @ W0^T + b0) ----------------
__global__ __launch_bounds__(256) void k_lin0(const float* __restrict__ x,
                                              const float* __restrict__ W0,
                                              const float* __restrict__ b0,
                                              float* __restrict__ feat) {
  __shared__ float w0t[1024];
  int t = threadIdx.x;
  for (int idx = t; idx < 1024; idx += 256) {
    int o = idx >> 5, i = idx & 31;
    w0t[(i << 5) | o] = W0[idx];
  }
  __syncthreads();
  int id = blockIdx.x * 256 + t;
  int n = id >> 5, o = id & 31;
  const float* xr = x + n * H;
  float acc = b0[o];
#pragma unroll
  for (int i = 0; i < H; ++i) acc = fmaf(xr[i], w0t[(i << 5) | o], acc);
  feat[id] = fmaxf(acc, 0.f);
}

// ---- CSR build ----
__global__ __launch_bounds__(256) void k_hist(const int* __restrict__ ei,
                                              int* __restrict__ deg) {
  int e = blockIdx.x * 256 + threadIdx.x;
  if (e < NE) atomicAdd(&deg[ei[e]], 1);
}

__global__ __launch_bounds__(256) void k_bsum(const int* __restrict__ deg,
                                              int* __restrict__ bsum) {
  __shared__ int red[256];
  int b = blockIdx.x, t = threadIdx.x;
  int base = b * SCB;
  int s = 0;
#pragma unroll
  for (int k = 0; k < 4; ++k) {
    int i = base + k * 256 + t;
    if (i < NN) s += deg[i];
  }
  red[t] = s;
  __syncthreads();
  for (int off = 128; off > 0; off >>= 1) {
    if (t < off) red[t] += red[t + off];
    __syncthreads();
  }
  if (t == 0) bsum[b] = red[0];
}

__global__ __launch_bounds__(128) void k_bscan(const int* __restrict__ bsum,
                                               int* __restrict__ boff,
                                               int* __restrict__ rowptr) {
  __shared__ int sh[128];
  int t = threadIdx.x;
  int v = (t < NBL) ? bsum[t] : 0;
  sh[t] = v;
  __syncthreads();
  for (int off = 1; off < 128; off <<= 1) {
    int u = (t >= off) ? sh[t - off] : 0;
    __syncthreads();
    sh[t] += u;
    __syncthreads();
  }
  if (t < NBL) boff[t] = sh[t] - v;
  if (t == 0) rowptr[NN] = NE;
}

__global__ __launch_bounds__(256) void k_rowptr(const int* __restrict__ deg,
                                                const int* __restrict__ boff,
                                                int* __restrict__ rowptr,
                                                int* __restrict__ nextp) {
  __shared__ int sh[256];
  int b = blockIdx.x, t = threadIdx.x;
  int base = b * SCB + t * 4;
  int d0 = 0, d1 = 0, d2 = 0, d3 = 0;
  if (base + 0 < NN) d0 = deg[base + 0];
  if (base + 1 < NN) d1 = deg[base + 1];
  if (base + 2 < NN) d2 = deg[base + 2];
  if (base + 3 < NN) d3 = deg[base + 3];
  int ts = d0 + d1 + d2 + d3;
  sh[t] = ts;
  __syncthreads();
  for (int off = 1; off < 256; off <<= 1) {
    int u = (t >= off) ? sh[t - off] : 0;
    __syncthreads();
    sh[t] += u;
    __syncthreads();
  }
  int run = boff[b] + sh[t] - ts;
  if (base + 0 < NN) { rowptr[base + 0] = run; nextp[base + 0] = run; run += d0; }
  if (base + 1 < NN) { rowptr[base + 1] = run; nextp[base + 1] = run; run += d1; }
  if (base + 2 < NN) { rowptr[base + 2] = run; nextp[base + 2] = run; run += d2; }
  if (base + 3 < NN) { rowptr[base + 3] = run; nextp[base + 3] = run; run += d3; }
}

__global__ __launch_bounds__(256) void k_scatter(const int* __restrict__ ei,
                                                 const float* __restrict__ ea,
                                                 int* __restrict__ nextp,
                                                 int* __restrict__ src_perm,
                                                 int* __restrict__ dst_perm,
                                                 float* __restrict__ ea_perm) {
  int e = blockIdx.x * 256 + threadIdx.x;
  if (e >= NE) return;
  int src = ei[e], dst = ei[NE + e];
  int p = atomicAdd(&nextp[src], 1);
  src_perm[p] = src;
  dst_perm[p] = dst;
  const float4* s4 = (const float4*)(ea + (size_t)e * ED);
  float4* d4 = (float4*)(ea_perm + (size_t)p * ED);
  d4[0] = s4[0]; d4[1] = s4[1]; d4[2] = s4[2]; d4[3] = s4[3];
}

// ---- weight pre-transpose (once): wcomb[i][192] = [WihT | WhhT], wrbe[i][64] = [WrootT | be] ----
__global__ __launch_bounds__(256) void k_prep(const float* __restrict__ Wih,
                                              const float* __restrict__ Whh,
                                              const float* __restrict__ Wroot,
                                              const float* __restrict__ be,
                                              float* __restrict__ wcomb,
                                              float* __restrict__ wrbe) {
  int idx = blockIdx.x * 256 + threadIdx.x;
  if (idx < 6144) {
    int i = idx / 192, o = idx % 192;
    wcomb[idx] = (o < 96) ? Wih[o * 32 + i] : Whh[(o - 96) * 32 + i];
  } else if (idx < 8192) {
    int r = idx - 6144;
    int i = r / 64, c = r % 64;
    wrbe[r] = (c < 32) ? Wroot[c * 32 + i] : be[i * 32 + (c - 32)];
  }
}

// ---- one-time agg/nodeb init before iteration 0 ----
__global__ __launch_bounds__(256) void k_pre_nb(const float* __restrict__ feat,
                                                const float* __restrict__ Wroot,
                                                const float* __restrict__ bconv,
                                                const float* __restrict__ be,
                                                float* __restrict__ agg,
                                                float* __restrict__ nodeb) {
  __shared__ float wrt[1024];
  int t = threadIdx.x;
  for (int idx = t; idx < 1024; idx += 256) {
    int o = idx >> 5, i = idx & 31;
    wrt[(i << 5) | o] = Wroot[idx];
  }
  __syncthreads();
  int id = blockIdx.x * 256 + t;
  int n = id >> 5, o = id & 31;
  const float* fr = feat + n * H;
  float a = bconv[o];
  float nb = 0.f;
#pragma unroll
  for (int i = 0; i < H; ++i) {
    float f = fr[i];
    a  = fmaf(f, wrt[(i << 5) | o], a);
    nb = fmaf(f, be[(i << 5) | o], nb);
  }
  agg[id]   = a;
  nodeb[id] = nb;
}

// ---- fused g+edge v4: coalesced We reads + XOR-swizzled sg (conflict-free both sides) ----
// Thread owns LOGICAL f4-column cj (consecutive lanes -> coalesced We4 load).
// Phys slot for logical s (o_c=s>>2, q_c=s&3):  P(s) = q_c*32 + (o_c ^ (q_c<<1)).
// Write: 8-lane group covers all 8 bank-quads (o_c^2q_c exhausts residues). ✓
// Read (output o, sub-slot q): addr = ln*128 + q*32 + (o ^ (q<<1)); 8 consecutive
// o -> 8 distinct bank-quads; ln*128 == 0 mod 8 so ln doesn't alias. ✓
__global__ __launch_bounds__(256) void k_fused(const float* __restrict__ feat,
                                               const float* __restrict__ We,
                                               const float* __restrict__ nodeb_g,
                                               const int* __restrict__ rowptr,
                                               const int* __restrict__ src_perm,
                                               const int* __restrict__ dst_perm,
                                               const float* __restrict__ ea_perm,
                                               float* __restrict__ agg) {
  __shared__ float4 sf4[NPB * 8];              // 2 KB
  __shared__ float  snb[NPB * 32];             // 2 KB
  __shared__ float4 sg4[NPB * 128];            // 32 KB
  int t = threadIdx.x;
  int base = blockIdx.x * NPB;

  if (t < 128) sf4[t] = ((const float4*)feat)[base * 8 + t];
  snb[t]       = nodeb_g[base * 32 + t];
  snb[t + 256] = nodeb_g[base * 32 + t + 256];
  __syncthreads();

  // g phase
  {
    int cj = t & 127, nh = t >> 7;
    const float4* We4 = (const float4*)We;     // [32][128], column cj coalesced
    float4 acc[8];
#pragma unroll
    for (int j = 0; j < 8; ++j) acc[j] = make_float4(0.f, 0.f, 0.f, 0.f);
#pragma unroll
    for (int i4 = 0; i4 < 8; ++i4) {
      float4 w0 = We4[(4 * i4 + 0) * 128 + cj];
      float4 w1 = We4[(4 * i4 + 1) * 128 + cj];
      float4 w2 = We4[(4 * i4 + 2) * 128 + cj];
      float4 w3 = We4[(4 * i4 + 3) * 128 + cj];
#pragma unroll
      for (int j = 0; j < 8; ++j) {
        float4 f = sf4[(nh * 8 + j) * 8 + i4];
        fma4(acc[j], f.x, w0);
        fma4(acc[j], f.y, w1);
        fma4(acc[j], f.z, w2);
        fma4(acc[j], f.w, w3);
      }
    }
    int pslot = (cj & 3) * 32 + ((cj >> 2) ^ ((cj & 3) << 1));
#pragma unroll
    for (int j = 0; j < 8; ++j) sg4[(nh * 8 + j) * 128 + pslot] = acc[j];
  }
  __syncthreads();

  // edge phase
  int e0 = rowptr[base], e1 = rowptr[base + NPB];
  int o = t & 31, slot = t >> 5;
  for (int e = e0 + slot; e < e1; e += 8) {
    int src = src_perm[e];
    int dst = dst_perm[e];
    int ln = src - base;
    const float4* e4 = (const float4*)(ea_perm + (size_t)e * ED);
    float acc = snb[ln * 32 + o];
#pragma unroll
    for (int q = 0; q < 4; ++q) {
      float4 gv = sg4[ln * 128 + q * 32 + (o ^ (q << 1))];
      float4 ev = e4[q];
      acc = fmaf(ev.x, gv.x, acc);
      acc = fmaf(ev.y, gv.y, acc);
      acc = fmaf(ev.z, gv.z, acc);
      acc = fmaf(ev.w, gv.w, acc);
    }
    unsafeAtomicAdd(&agg[(size_t)dst * 32 + o], acc);
  }
}

// ---- gru3: gates GEMM (lane=col, node-broadcast) + fused Wroot/be epilogue ----
__global__ __launch_bounds__(256) void k_gru3(float* __restrict__ agg,
                                              float* __restrict__ feat,
                                              const float* __restrict__ wcomb,
                                              const float* __restrict__ wrbe,
                                              const float* __restrict__ bih,
                                              const float* __restrict__ bhh,
                                              const float* __restrict__ bconv,
                                              float* __restrict__ nodeb,
                                              int do_pre) {
  __shared__ float4 wlds[1536];                // [32][48] f4 = 24 KB
  __shared__ float4 wrl[512];                  // [32][16] f4 = 8 KB
  __shared__ float4 sm4[NPB * 8];              // m = relu(agg)
  __shared__ float4 sh4[NPB * 8];              // h_old
  __shared__ float4 shn4[NPB * 8];             // h_new
  __shared__ float4 gl4[NPB * 48];             // [16][48] f4 = 12 KB
  int t = threadIdx.x;
  int base = blockIdx.x * NPB;

  for (int idx = t; idx < 1536; idx += 256) wlds[idx] = ((const float4*)wcomb)[idx];
  for (int idx = t; idx < 512; idx += 256)  wrl[idx]  = ((const float4*)wrbe)[idx];
  if (t < 128) {
    float4 a = ((const float4*)agg)[base * 8 + t];
    a.x = fmaxf(a.x, 0.f); a.y = fmaxf(a.y, 0.f);
    a.z = fmaxf(a.z, 0.f); a.w = fmaxf(a.w, 0.f);
    sm4[t] = a;
    sh4[t] = ((const float4*)feat)[base * 8 + t];
  }
  __syncthreads();

  int wv = t >> 6, lane = t & 63;
  int ln0 = wv * 4;                            // 4 nodes per wave

  // phase A: gi/gh GEMM. lane<24: gi col=lane (input m); 24..47: gh col (input h)
  if (lane < 48) {
    const float4* S4 = (lane < 24) ? sm4 : sh4;
    float4 a0 = make_float4(0.f,0.f,0.f,0.f), a1 = a0, a2 = a0, a3 = a0;
#pragma unroll
    for (int i4 = 0; i4 < 8; ++i4) {
      float4 w0 = wlds[(4 * i4 + 0) * 48 + lane];
      float4 w1 = wlds[(4 * i4 + 1) * 48 + lane];
      float4 w2 = wlds[(4 * i4 + 2) * 48 + lane];
      float4 w3 = wlds[(4 * i4 + 3) * 48 + lane];
      float4 f0 = S4[(ln0 + 0) * 8 + i4];
      float4 f1 = S4[(ln0 + 1) * 8 + i4];
      float4 f2 = S4[(ln0 + 2) * 8 + i4];
      float4 f3 = S4[(ln0 + 3) * 8 + i4];
      fma4(a0, f0.x, w0); fma4(a0, f0.y, w1); fma4(a0, f0.z, w2); fma4(a0, f0.w, w3);
      fma4(a1, f1.x, w0); fma4(a1, f1.y, w1); fma4(a1, f1.z, w2); fma4(a1, f1.w, w3);
      fma4(a2, f2.x, w0); fma4(a2, f2.y, w1); fma4(a2, f2.z, w2); fma4(a2, f2.w, w3);
      fma4(a3, f3.x, w0); fma4(a3, f3.y, w1); fma4(a3, f3.z, w2); fma4(a3, f3.w, w3);
    }
    gl4[(ln0 + 0) * 48 + lane] = a0;
    gl4[(ln0 + 1) * 48 + lane] = a1;
    gl4[(ln0 + 2) * 48 + lane] = a2;
    gl4[(ln0 + 3) * 48 + lane] = a3;
  }
  __syncthreads();

  // phase B: gates elementwise (128 f4-items), write h_new
  if (t < 128) {
    int ln = t >> 3, o4 = t & 7;
    const float4* Bi = (const float4*)bih;
    const float4* Bh = (const float4*)bhh;
    float4 ir = gl4[ln * 48 + o4],       bi0 = Bi[o4];
    float4 iz = gl4[ln * 48 + 8 + o4],   bi1 = Bi[8 + o4];
    float4 in_ = gl4[ln * 48 + 16 + o4], bi2 = Bi[16 + o4];
    float4 hr = gl4[ln * 48 + 24 + o4],  bh0 = Bh[o4];
    float4 hz = gl4[ln * 48 + 32 + o4],  bh1 = Bh[8 + o4];
    float4 hn = gl4[ln * 48 + 40 + o4],  bh2 = Bh[16 + o4];
    float4 h = sh4[ln * 8 + o4];
    float4 out;
#define GATE(c) { \
    float grv = 1.f / (1.f + expf(-((ir.c + bi0.c) + (hr.c + bh0.c)))); \
    float gzv = 1.f / (1.f + expf(-((iz.c + bi1.c) + (hz.c + bh1.c)))); \
    float gnv = tanhf((in_.c + bi2.c) + grv * (hn.c + bh2.c)); \
    out.c = (1.f - gzv) * gnv + gzv * h.c; }
    GATE(x) GATE(y) GATE(z) GATE(w)
#undef GATE
    shn4[ln * 8 + o4] = out;
    ((float4*)feat)[base * 8 + t] = out;
  }
  __syncthreads();

  // phase C: agg_init = h_new @ WrootT + bconv ; nodeb = h_new @ be-matrix
  if (do_pre) {
    int col = lane & 15, nsub = lane >> 4;
    int ln = ln0 + nsub;
    float4 acc = make_float4(0.f, 0.f, 0.f, 0.f);
#pragma unroll
    for (int i4 = 0; i4 < 8; ++i4) {
      float4 f  = shn4[ln * 8 + i4];
      float4 w0 = wrl[(4 * i4 + 0) * 16 + col];
      float4 w1 = wrl[(4 * i4 + 1) * 16 + col];
      float4 w2 = wrl[(4 * i4 + 2) * 16 + col];
      float4 w3 = wrl[(4 * i4 + 3) * 16 + col];
      fma4(acc, f.x, w0); fma4(acc, f.y, w1); fma4(acc, f.z, w2); fma4(acc, f.w, w3);
    }
    if (col < 8) {
      float4 bc = ((const float4*)bconv)[col];
      acc.x += bc.x; acc.y += bc.y; acc.z += bc.z; acc.w += bc.w;
      ((float4*)agg)[(base + ln) * 8 + col] = acc;
    } else {
      ((float4*)nodeb)[(base + ln) * 8 + (col - 8)] = acc;
    }
  }
}

// ---- global mean pool ----
__global__ __launch_bounds__(256) void k_pool(const float* __restrict__ feat,
                                              const int* __restrict__ batch,
                                              float* __restrict__ pooled,
                                              float* __restrict__ cnts) {
  int id = blockIdx.x * 256 + threadIdx.x;
  int n = id >> 5, o = id & 31;
  int b = batch[n];
  unsafeAtomicAdd(&pooled[b * H + o], feat[id]);
  if (o == 0) unsafeAtomicAdd(&cnts[b], 1.f);
}

// ---- final head ----
__global__ __launch_bounds__(256) void k_final(const float* __restrict__ pooled,
                                               const float* __restrict__ cnts,
                                               const float* __restrict__ W1,
                                               const float* __restrict__ b1,
                                               float* __restrict__ y) {
  int gph = blockIdx.x * 256 + threadIdx.x;
  if (gph >= NG) return;
  float c = fmaxf(cnts[gph], 1.f);
  float acc = 0.f;
#pragma unroll
  for (int o = 0; o < H; ++o) acc = fmaf(pooled[gph * H + o], W1[o], acc);
  y[gph] = acc / c + b1[0];
}

extern "C" void kernel_launch(void* const* d_in, const int* in_sizes, int n_in,
                              void* d_out, int out_size, void* d_ws, size_t ws_size,
                              hipStream_t stream) {
  const float* x     = (const float*)d_in[0];
  const int*   ei    = (const int*)d_in[1];
  const float* ea    = (const float*)d_in[2];
  const int*   batch = (const int*)d_in[3];
  const float* W0    = (const float*)d_in[4];
  const float* b0    = (const float*)d_in[5];
  const float* We    = (const float*)d_in[6];
  const float* be    = (const float*)d_in[7];
  const float* Wroot = (const float*)d_in[8];
  const float* bconv = (const float*)d_in[9];
  const float* Wih   = (const float*)d_in[10];
  const float* bih   = (const float*)d_in[11];
  const float* Whh   = (const float*)d_in[12];
  const float* bhh   = (const float*)d_in[13];
  const float* W1    = (const float*)d_in[14];
  const float* b1    = (const float*)d_in[15];

  float* ws       = (float*)d_ws;
  float* feat     = ws;                         // 3,200,000
  float* agg      = ws + 3200000;               // 3,200,000
  float* nodeb    = ws + 6400000;               // 3,200,000
  float* pooled   = ws + 9600000;               // 65,536
  float* cnts     = ws + 9665536;               // 2,048
  float* wcomb    = ws + 9667584;               // 6,144
  float* wrbe     = ws + 9673728;               // 2,048
  float* ea_perm  = ws + 9675776;               // 6,400,000 (16B aligned)
  int*   ibuf     = (int*)(ws + 16075776);
  int*   deg      = ibuf;                       // 100,000
  int*   rowptr   = ibuf + 100000;              // 100,001
  int*   nextp    = ibuf + 200004;              // 100,000
  int*   src_perm = ibuf + 300004;              // 400,000
  int*   dst_perm = ibuf + 700004;              // 400,000
  int*   bsum     = ibuf + 1100004;             // 98
  int*   boff     = ibuf + 1100104;             // 98

  const int NB_NODE = (NN * H) / 256;           // 12500
  const int NB_E    = (NE + 255) / 256;         // 1563

  // one-time CSR build + weight transpose
  hipMemsetAsync(deg, 0, NN * sizeof(int), stream);
  k_hist<<<NB_E, 256, 0, stream>>>(ei, deg);
  k_bsum<<<NBL, 256, 0, stream>>>(deg, bsum);
  k_bscan<<<1, 128, 0, stream>>>(bsum, boff, rowptr);
  k_rowptr<<<NBL, 256, 0, stream>>>(deg, boff, rowptr, nextp);
  k_scatter<<<NB_E, 256, 0, stream>>>(ei, ea, nextp, src_perm, dst_perm, ea_perm);
  k_prep<<<32, 256, 0, stream>>>(Wih, Whh, Wroot, be, wcomb, wrbe);

  k_lin0<<<NB_NODE, 256, 0, stream>>>(x, W0, b0, feat);
  k_pre_nb<<<NB_NODE, 256, 0, stream>>>(feat, Wroot, bconv, be, agg, nodeb);
  for (int it = 0; it < 3; ++it) {
    k_fused<<<NN / NPB, 256, 0, stream>>>(feat, We, nodeb, rowptr, src_perm,
                                          dst_perm, ea_perm, agg);
    k_gru3<<<NN / NPB, 256, 0, stream>>>(agg, feat, wcomb, wrbe, bih, bhh, bconv,
                                         nodeb, it < 2 ? 1 : 0);
  }
  hipMemsetAsync(pooled, 0, (size_t)(NG * H + NG) * 4, stream);
  k_pool<<<NB_NODE, 256, 0, stream>>>(feat, batch, pooled, cnts);
  k_final<<<(NG + 255) / 256, 256, 0, stream>>>(pooled, cnts, W1, b1, (float*)d_out);
}